// Round 2
// baseline (1101.385 us; speedup 1.0000x reference)
//
#include <hip/hip_runtime.h>

// PrimaryCaps: u[b,c,o] = sum_i x[b,c,i] * W[c,i,o] + bias[c,o]
// B=64, C=4096, IN=512, OUT=16.  fp32 in / fp32 out.
//
// Memory-bound problem: x=512MB + W=128MB + out=16MB ~= 656MB -> ~104us floor
// at 6.3 TB/s.  Strategy: one wave per capsule (4096 blocks x 64 threads).
// Lane t: cg = t&3 -> output cols [cg*4, cg*4+4); rg = t>>2 -> batch rows
// {rg, rg+16, rg+32, rg+48}.  One wave covers the whole 64x16 tile, so:
//  - W[c] is read via 16-way same-address broadcast (one HBM fetch, no LDS)
//  - x rows are read via 4-way broadcast, float4 per k-step
//  - 16 accumulators per lane, no barriers, no LDS.

#define N_CAPS 4096
#define IN_DIM 512
#define OUT_DIM 16
#define BATCH 64

__device__ __forceinline__ void fma4(float4& a, float s, const float4& v) {
    a.x = fmaf(s, v.x, a.x);
    a.y = fmaf(s, v.y, a.y);
    a.z = fmaf(s, v.z, a.z);
    a.w = fmaf(s, v.w, a.w);
}

__global__ __launch_bounds__(64, 4)
void primary_caps_kernel(const float* __restrict__ x,
                         const float* __restrict__ W,
                         const float* __restrict__ bias,
                         float* __restrict__ out) {
    const int c  = blockIdx.x;        // capsule
    const int t  = threadIdx.x;       // 0..63
    const int cg = t & 3;             // col group (4 cols)
    const int rg = t >> 2;            // row group (rows rg + 16*r)

    const float4* x4 = (const float4*)x;
    const float4* W4 = (const float4*)W;
    const float4* b4 = (const float4*)bias;
    float4*       o4 = (float4*)out;

    // bias for this lane's 4 columns
    const float4 bv = b4[(size_t)c * (OUT_DIM / 4) + cg];
    float4 acc[4];
#pragma unroll
    for (int r = 0; r < 4; ++r) acc[r] = bv;

    // x row pointers (float4 granularity): x[b, c, :] contiguous, 512 floats
    const float4* xp[4];
#pragma unroll
    for (int r = 0; r < 4; ++r) {
        const size_t b = (size_t)(rg + 16 * r);
        xp[r] = x4 + (b * N_CAPS + c) * (IN_DIM / 4);
    }
    // W pointer: W[c, i, o]; float4 index = (c*512 + i)*4 + cg
    const float4* wp = W4 + (size_t)c * (IN_DIM * OUT_DIM / 4) + cg;

#pragma unroll 2
    for (int i4 = 0; i4 < IN_DIM / 4; ++i4) {
        // W rows k = 4*i4 .. 4*i4+3, this lane's 4 columns each
        float4 w0 = wp[i4 * 16 + 0];
        float4 w1 = wp[i4 * 16 + 4];
        float4 w2 = wp[i4 * 16 + 8];
        float4 w3 = wp[i4 * 16 + 12];
#pragma unroll
        for (int r = 0; r < 4; ++r) {
            const float4 xv = xp[r][i4];
            fma4(acc[r], xv.x, w0);
            fma4(acc[r], xv.y, w1);
            fma4(acc[r], xv.z, w2);
            fma4(acc[r], xv.w, w3);
        }
    }

    // store: u[b, c, o] -> float4 index (b*C + c)*4 + cg
#pragma unroll
    for (int r = 0; r < 4; ++r) {
        const size_t b = (size_t)(rg + 16 * r);
        o4[(b * N_CAPS + c) * (OUT_DIM / 4) + cg] = acc[r];
    }
}

extern "C" void kernel_launch(void* const* d_in, const int* in_sizes, int n_in,
                              void* d_out, int out_size, void* d_ws, size_t ws_size,
                              hipStream_t stream) {
    const float* x    = (const float*)d_in[0];
    const float* W    = (const float*)d_in[1];
    const float* bias = (const float*)d_in[2];
    float*       out  = (float*)d_out;

    primary_caps_kernel<<<N_CAPS, 64, 0, stream>>>(x, W, bias, out);
}